// Round 15
// baseline (46.081 us; speedup 1.0000x reference)
//
#include <hip/hip_runtime.h>
#include <hip/hip_bf16.h>
#include <cstddef>

namespace {

constexpr int NB    = 8;
constexpr int LQn   = 2048;
constexpr int DM    = 256;
constexpr int S_TOT = 3840;   // 2048+1024+512+256
constexpr int BK    = 32;

typedef __attribute__((ext_vector_type(8))) short  short8;
typedef __attribute__((ext_vector_type(4))) float  f32x4;
typedef __attribute__((ext_vector_type(8))) _Float16 half8;
typedef __attribute__((ext_vector_type(4))) _Float16 half4;
typedef __attribute__((ext_vector_type(2))) _Float16 half2v;

// pack 4+4 f32 -> 8 bf16 via native v_cvt_pk_bf16_f32
union BF8 { __hip_bfloat162 h2[4]; short8 s8; };
__device__ inline short8 cvt8(const f32x4 a, const f32x4 b) {
  BF8 r;
  r.h2[0] = __float22bfloat162_rn(make_float2(a[0], a[1]));
  r.h2[1] = __float22bfloat162_rn(make_float2(a[2], a[3]));
  r.h2[2] = __float22bfloat162_rn(make_float2(b[0], b[1]));
  r.h2[3] = __float22bfloat162_rn(make_float2(b[2], b[3]));
  return r.s8;
}

// ---------------------------------------------------------------------------
// Merged bf16-MFMA GEMM, R15: DOUBLE-BUFFERED LDS, ONE barrier per k-step
// (was 2), MFMA-FIRST ordering. Iter k:
//   MFMA(buf[k&1]) -> stage buf[(k+1)&1] (W JIT-load + A cvt) ->
//   issue A(k+2) HBM loads -> lgkmcnt(0) -> s_barrier.
// W's ~300cy L2 latency now lands AFTER the MFMA issue burst (hidden by
// co-resident waves' MFMA; was serial on the critical path every k-step),
// and barrier drains halve 16 -> 8. A prefetch still rides across barriers
// (vmcnt never drained -- only lgkmcnt). Race check: MFMA(k)'s frag reads
// retire before the wave reaches barrier k, so stage(k+2)'s overwrite of
// buf[k&1] in iter k+1 is safe with a single barrier.
// Rest as R12: tile 128x256 (A read once), 512 thr / 8 waves (2m x 4n),
// BK=32, k-major LDS (conflict-free frags), XCD-aligned (id%8 = batch),
// head-major value epilogue. Measured R13: G = 18.4 us, floor ~12.
// ---------------------------------------------------------------------------
union SMem {
  struct { short A[2][4 * 128 * 8]; short B[2][4 * 256 * 8]; } ab;  // 48 KB
  _Float16 c[128 * 136];                                             // 34 KB
};

__global__ __launch_bounds__(512, 4) void gemm_bf16_k(
    const float* __restrict__ A_val, const float* __restrict__ A_prj,
    const float* __restrict__ W_val, const float* __restrict__ b_val,
    const float* __restrict__ W_off, const float* __restrict__ b_off,
    const float* __restrict__ W_att, const float* __restrict__ b_att,
    _Float16* __restrict__ out_val, _Float16* __restrict__ out_prj)
{
  __shared__ SMem sm;

  const int tid  = threadIdx.x;
  const int lane = tid & 63;
  const int wid  = tid >> 6;     // 0..7
  const int wm   = wid >> 2;     // 0..1
  const int wn   = wid & 3;      // 0..3

  const int id = blockIdx.x;
  const float* A;
  bool isv;
  int r0, vbatch = 0, vtrow0 = 0;
  if (id < 240) {
    const int x = id & 7;        // XCD == batch
    const int s = id >> 3;       // 0..29
    A = A_val; r0 = (x * 30 + s) * 128;
    isv = true; vbatch = x; vtrow0 = s * 128;
  } else {
    const int j = id - 240;
    const int x = j & 7;
    const int s = j >> 3;        // 0..15
    A = A_prj; r0 = (x * 16 + s) * 128;
    isv = false;
  }

  float bv[4];
  #pragma unroll
  for (int ni = 0; ni < 4; ++ni) {
    const int col = wn * 64 + ni * 16 + (lane & 15);
    bv[ni] = isv ? b_val[col]
                 : (col < 128 ? b_off[col] : b_att[col - 128]);
  }

  const int arow = tid >> 2;     // 0..127
  const int akg  = tid & 3;      // 0..3

  const float* wrow0;
  const float* wrow1;
  if (isv) {
    wrow0 = W_val + (size_t)arow * DM;
    wrow1 = W_val + (size_t)(arow + 128) * DM;
  } else {
    wrow0 = W_off + (size_t)arow * DM;
    wrow1 = W_att + (size_t)arow * DM;
  }

  f32x4 pa0, pa1;   // A prefetch regs (hold A(k+1) during iter k)
  auto load_A = [&](int k0) {
    const float* p = &A[(size_t)(r0 + arow) * DM + k0 + akg * 8];
    pa0 = *reinterpret_cast<const f32x4*>(p);
    pa1 = *reinterpret_cast<const f32x4*>(p + 4);
  };

  // stage k-tile (W JIT + A from pa) into buffer b
  auto stage = [&](int b, int k0) {
    char* As = reinterpret_cast<char*>(sm.ab.A[b]);
    char* Bs = reinterpret_cast<char*>(sm.ab.B[b]);
    const float* p0 = wrow0 + k0 + akg * 8;
    const f32x4 w00 = *reinterpret_cast<const f32x4*>(p0);
    const f32x4 w01 = *reinterpret_cast<const f32x4*>(p0 + 4);
    *reinterpret_cast<short8*>(Bs + akg * 4096 + arow * 16) = cvt8(w00, w01);
    const float* p1 = wrow1 + k0 + akg * 8;
    const f32x4 w10 = *reinterpret_cast<const f32x4*>(p1);
    const f32x4 w11 = *reinterpret_cast<const f32x4*>(p1 + 4);
    *reinterpret_cast<short8*>(Bs + akg * 4096 + (arow + 128) * 16) =
        cvt8(w10, w11);
    *reinterpret_cast<short8*>(As + akg * 2048 + arow * 16) = cvt8(pa0, pa1);
  };

  f32x4 acc[4][4] = {};

  // ---- prologue: stage buf0 with k=0; prefetch A(1) ----
  load_A(0);
  stage(0, 0);
  load_A(BK);
  asm volatile("s_waitcnt lgkmcnt(0)" ::: "memory");
  __builtin_amdgcn_sched_barrier(0);
  __builtin_amdgcn_s_barrier();
  __builtin_amdgcn_sched_barrier(0);

  for (int k = 0; k < 8; ++k) {
    // ---- MFMA from buf[k&1] ----
    {
      const char* As = reinterpret_cast<const char*>(sm.ab.A[k & 1]);
      const char* Bs = reinterpret_cast<const char*>(sm.ab.B[k & 1]);
      const int kgl = lane >> 4;     // 0..3
      const int rl  = lane & 15;
      short8 af[4], bfr[4];
      #pragma unroll
      for (int mi = 0; mi < 4; ++mi)
        af[mi] = *reinterpret_cast<const short8*>(
            As + kgl * 2048 + (wm * 64 + mi * 16 + rl) * 16);
      #pragma unroll
      for (int ni = 0; ni < 4; ++ni)
        bfr[ni] = *reinterpret_cast<const short8*>(
            Bs + kgl * 4096 + (wn * 64 + ni * 16 + rl) * 16);
      #pragma unroll
      for (int mi = 0; mi < 4; ++mi)
        #pragma unroll
        for (int ni = 0; ni < 4; ++ni)
          acc[mi][ni] = __builtin_amdgcn_mfma_f32_16x16x32_bf16(
              af[mi], bfr[ni], acc[mi][ni], 0, 0, 0);
    }

    if (k < 7) {
      // ---- stage k+1 into the other buffer (W L2 latency hides under
      //      co-resident waves' MFMA); issue A(k+2); one barrier ----
      stage((k + 1) & 1, (k + 1) * BK);
      if (k < 6) load_A((k + 2) * BK);
      asm volatile("s_waitcnt lgkmcnt(0)" ::: "memory");
      __builtin_amdgcn_sched_barrier(0);
      __builtin_amdgcn_s_barrier();
      __builtin_amdgcn_sched_barrier(0);
    }
  }

  // ---- epilogue: acc -> f16 LDS tile -> coalesced stores ----
  __syncthreads();   // all frag reads done before LDS reuse
  #pragma unroll
  for (int hh = 0; hh < 2; ++hh) {
    if ((wn >> 1) == hh) {
      #pragma unroll
      for (int mi = 0; mi < 4; ++mi) {
        const int row = wm * 64 + mi * 16 + (lane >> 4) * 4;
        #pragma unroll
        for (int ni = 0; ni < 4; ++ni) {
          const int coll = (wn & 1) * 64 + ni * 16 + (lane & 15);
          #pragma unroll
          for (int j = 0; j < 4; ++j)
            sm.c[(row + j) * 136 + coll] = (_Float16)(acc[mi][ni][j] + bv[ni]);
        }
      }
    }
    __syncthreads();
    #pragma unroll
    for (int i = 0; i < 4; ++i) {
      const int ch  = tid + i * 512;   // 0..2047
      const int row = ch >> 4;         // 0..127
      const int cc  = ch & 15;
      const half8 v = *reinterpret_cast<const half8*>(&sm.c[row * 136 + cc * 8]);
      if (isv) {
        const int h = hh * 4 + (cc >> 2);
        _Float16* dst = out_val +
            ((size_t)(vbatch * 8 + h) * S_TOT + vtrow0 + row) * 32 + (cc & 3) * 8;
        *reinterpret_cast<half8*>(dst) = v;
      } else {
        *reinterpret_cast<half8*>(
            &out_prj[(size_t)(r0 + row) * DM + hh * 128 + cc * 8]) = v;
      }
    }
    __syncthreads();
  }
}

// ---------------------------------------------------------------------------
// Sampler v7 (unchanged R14). Measured S ~= 23.7 us, invariant under MLP
// depth (R10), layout (R11), and segment-size (R14) restructures ->
// scattered-gather granule-rate floor (~11.3 TB/s effective); not touched.
// ---------------------------------------------------------------------------
__global__ __launch_bounds__(512) void sample_k(
    const _Float16* __restrict__ proj,    // (N*LQ, 256) f16
    const float* __restrict__ refp,       // (N, LQ, 4)
    const _Float16* __restrict__ value,   // (N, 8, 3840, 32) f16 head-major
    float* __restrict__ out)              // (N, LQ, 256)
{
  __shared__ uint2 tap_s[8][136];   // [q][m*17 + tap], 8.7 KB

  const int d     = blockIdx.x;
  const int n     = d & 7;
  const int chunk = d >> 3;
  const int row0q = n * LQn + chunk * 8;
  const int t     = threadIdx.x;

  const int lens[4]   = {2048, 1024, 512, 256};
  const int starts[4] = {0, 2048, 3072, 3584};

  if (t < 256) {
    const int q   = t >> 5;
    const int m   = (t >> 2) & 7;
    const int sub = t & 3;              // == level l
    const int j0  = m * 16 + sub * 4;
    const size_t prow = (size_t)(row0q + q) * DM;

    const half4 offv = *reinterpret_cast<const half4*>(&proj[prow + j0]);
    const half4 lgv  = *reinterpret_cast<const half4*>(&proj[prow + 128 + j0]);
    float lg[4], off[4];
    #pragma unroll
    for (int i = 0; i < 4; ++i) { lg[i] = (float)lgv[i]; off[i] = (float)offv[i]; }

    float mx = fmaxf(fmaxf(lg[0], lg[1]), fmaxf(lg[2], lg[3]));
    mx = fmaxf(mx, __shfl_xor(mx, 1));
    mx = fmaxf(mx, __shfl_xor(mx, 2));
    float e[4], s = 0.f;
    #pragma unroll
    for (int i = 0; i < 4; ++i) { e[i] = __expf(lg[i] - mx); s += e[i]; }
    s += __shfl_xor(s, 1);
    s += __shfl_xor(s, 2);
    const float inv = 1.f / s;

    const int   T  = lens[sub];
    const int   st = starts[sub];
    const float fT = (float)T;
    const float rf = refp[(size_t)(row0q + q) * 4 + sub];
    #pragma unroll
    for (int i = 0; i < 4; ++i) {
      const float a  = e[i] * inv;
      const float ix = fmaf(rf, fT, off[i] - 0.5f);
      const float fl = floorf(ix);
      const float w1 = ix - fl;
      const int   i0 = (int)fl;
      const int   i1 = i0 + 1;
      const float wa = (i0 >= 0 && i0 < T) ? a * (1.f - w1) : 0.f;
      const float wb = (i1 >= 0 && i1 < T) ? a * w1 : 0.f;
      const int   base = min(max(i0, 0), T - 2);
      const float w_lo = (i0 == base) ? wa : ((i1 == base) ? wb : 0.f);
      const float w_hi = (i1 == base + 1) ? wb : ((i0 == base + 1) ? wa : 0.f);
      union { half2v h; unsigned u; } pw;
      pw.h.x = (_Float16)w_lo; pw.h.y = (_Float16)w_hi;
      uint2 ent; ent.x = pw.u; ent.y = (unsigned)((st + base) * 64);
      tap_s[q][m * 17 + sub * 4 + i] = ent;
    }
  }
  __syncthreads();

  const int q = t >> 6;           // wave id = query
  const int l = t & 63;
  const int m = l >> 3;           // head
  const int j = l & 7;            // 0..3 row base chunks, 4..7 row base+1
  const char* vb = reinterpret_cast<const char*>(value) +
                   (size_t)(n * 8 + m) * S_TOT * 64 + j * 16;

  uint2 e[16];
  #pragma unroll
  for (int i = 0; i < 16; ++i) e[i] = tap_s[q][m * 17 + i];

  float acc[8] = {};
  half8 v[8];
  #pragma unroll
  for (int i = 0; i < 8; ++i)
    v[i] = *reinterpret_cast<const half8*>(vb + e[i].y);

  #pragma unroll
  for (int i = 0; i < 16; ++i) {
    union { unsigned u; half2v h; } pw; pw.u = e[i].x;
    const float w = (float)((l & 4) ? pw.h.y : pw.h.x);
    const half8 a0 = v[i & 7];
    if (i < 8)
      v[i & 7] = *reinterpret_cast<const half8*>(vb + e[i + 8].y);
    #pragma unroll
    for (int jj = 0; jj < 8; ++jj)
      acc[jj] = fmaf(w, (float)a0[jj], acc[jj]);
  }

  #pragma unroll
  for (int jj = 0; jj < 8; ++jj) acc[jj] += __shfl_xor(acc[jj], 4);

  if ((l & 4) == 0) {
    float* op = &out[(size_t)(row0q + q) * DM + m * 32 + j * 8];
    f32x4 o0 = {acc[0], acc[1], acc[2], acc[3]};
    f32x4 o1 = {acc[4], acc[5], acc[6], acc[7]};
    *reinterpret_cast<f32x4*>(op)     = o0;
    *reinterpret_cast<f32x4*>(op + 4) = o1;
  }
}

}  // namespace

extern "C" void kernel_launch(void* const* d_in, const int* in_sizes, int n_in,
                              void* d_out, int out_size, void* d_ws, size_t ws_size,
                              hipStream_t stream) {
  const float* query  = (const float*)d_in[0];   // (8,2048,256)
  const float* refp   = (const float*)d_in[1];   // (8,2048,4,1)
  const float* inflat = (const float*)d_in[2];   // (8,3840,256)
  const float* W_val  = (const float*)d_in[5];   // (256,256)
  const float* b_val  = (const float*)d_in[6];   // (256,)
  const float* W_off  = (const float*)d_in[7];   // (128,256)
  const float* b_off  = (const float*)d_in[8];   // (128,)
  const float* W_attn = (const float*)d_in[9];   // (128,256)
  const float* b_attn = (const float*)d_in[10];  // (128,)
  float* out = (float*)d_out;

  _Float16* value_h = (_Float16*)d_ws;
  _Float16* proj_h  = (_Float16*)((char*)d_ws +
                      (size_t)NB * S_TOT * DM * sizeof(_Float16));

  // merged GEMM: 240 value blocks + 128 proj blocks (A read once),
  // XCD-aligned, double-buffered single-barrier pipeline
  gemm_bf16_k<<<dim3(368), dim3(512), 0, stream>>>(
      inflat, query, W_val, b_val, W_off, b_off, W_attn, b_attn,
      value_h, proj_h);

  // sampler v7: 128 B-contiguous tap loads
  sample_k<<<dim3(NB * LQn / 8), dim3(512), 0, stream>>>(
      proj_h, refp, value_h, out);
}

// Round 16
// 43.176 us; speedup vs baseline: 1.0673x; 1.0673x over previous
//
#include <hip/hip_runtime.h>
#include <hip/hip_bf16.h>
#include <cstddef>

namespace {

constexpr int NB    = 8;
constexpr int LQn   = 2048;
constexpr int DM    = 256;
constexpr int S_TOT = 3840;   // 2048+1024+512+256
constexpr int BK    = 32;

typedef __attribute__((ext_vector_type(8))) short  short8;
typedef __attribute__((ext_vector_type(4))) float  f32x4;
typedef __attribute__((ext_vector_type(8))) _Float16 half8;
typedef __attribute__((ext_vector_type(4))) _Float16 half4;
typedef __attribute__((ext_vector_type(2))) _Float16 half2v;

// pack 4+4 f32 -> 8 bf16 via native v_cvt_pk_bf16_f32
union BF8 { __hip_bfloat162 h2[4]; short8 s8; };
__device__ inline short8 cvt8(const f32x4 a, const f32x4 b) {
  BF8 r;
  r.h2[0] = __float22bfloat162_rn(make_float2(a[0], a[1]));
  r.h2[1] = __float22bfloat162_rn(make_float2(a[2], a[3]));
  r.h2[2] = __float22bfloat162_rn(make_float2(b[0], b[1]));
  r.h2[3] = __float22bfloat162_rn(make_float2(b[2], b[3]));
  return r.s8;
}

// ---------------------------------------------------------------------------
// Merged bf16-MFMA GEMM, R16: tile 64 x 256 for LOAD BALANCE. R12's 368
// blocks XCD-pinned = 46 blocks per 32-CU XCD -> 14 CUs run 2 blocks, 18 run
// 1 -> makespan ~2 block-times, 72% CU utilization (explains G=18.4 vs ~13
// floor; also why R12's A-traffic halving was null -- it traded balance).
// 64-row tiles: 736 blocks -> 92/XCD -> 2.875/CU, ALL co-resident (20 KB
// LDS, acc=32 VGPR, 4 blocks/CU capacity) -> ~96% utilization.
// 512 thr = 8 waves (2m x 4n), wave tile 32x64, BK=32, 8 k-steps.
// A read once per row-panel (reg-prefetch, threads 0-255 stage the 4 KB
// tile); W JIT-staged from L2 (same 2-chunk pattern as R12). k-major LDS,
// R12's proven 2-barrier k-step (R15's dbuf regressed -- reverted).
// XCD-aligned (id%8 = batch), head-major value epilogue.
// ---------------------------------------------------------------------------
union SMem {
  struct { short A[4 * 64 * 8]; short B[4 * 256 * 8]; } ab;   // 4 + 16 KB
  _Float16 c[64 * 136];                                        // 17.4 KB epi
};

__global__ __launch_bounds__(512, 4) void gemm_bf16_k(
    const float* __restrict__ A_val, const float* __restrict__ A_prj,
    const float* __restrict__ W_val, const float* __restrict__ b_val,
    const float* __restrict__ W_off, const float* __restrict__ b_off,
    const float* __restrict__ W_att, const float* __restrict__ b_att,
    _Float16* __restrict__ out_val, _Float16* __restrict__ out_prj)
{
  __shared__ SMem sm;
  char* As = reinterpret_cast<char*>(sm.ab.A);
  char* Bs = reinterpret_cast<char*>(sm.ab.B);

  const int tid  = threadIdx.x;
  const int lane = tid & 63;
  const int wid  = tid >> 6;     // 0..7
  const int wm   = wid >> 2;     // 0..1  (rows wm*32 + mi*16)
  const int wn   = wid & 3;      // 0..3  (cols wn*64 + ni*16)

  const int id = blockIdx.x;
  const float* A;
  bool isv;
  int r0, vbatch = 0, vtrow0 = 0;
  if (id < 480) {
    const int x = id & 7;        // XCD == batch
    const int s = id >> 3;       // 0..59
    A = A_val; r0 = (x * 60 + s) * 64;
    isv = true; vbatch = x; vtrow0 = s * 64;
  } else {
    const int j = id - 480;
    const int x = j & 7;
    const int s = j >> 3;        // 0..31
    A = A_prj; r0 = (x * 32 + s) * 64;
    isv = false;
  }

  float bv[4];
  #pragma unroll
  for (int ni = 0; ni < 4; ++ni) {
    const int col = wn * 64 + ni * 16 + (lane & 15);
    bv[ni] = isv ? b_val[col]
                 : (col < 128 ? b_off[col] : b_att[col - 128]);
  }

  // W staging: 1024 chunks (256 rows x 4 kg), 2 per thread (rows wr, wr+128)
  const int wr  = tid >> 2;      // 0..127
  const int wkg = tid & 3;       // 0..3
  const float* wrow0;
  const float* wrow1;
  if (isv) {
    wrow0 = W_val + (size_t)wr * DM;
    wrow1 = W_val + (size_t)(wr + 128) * DM;
  } else {
    wrow0 = W_off + (size_t)wr * DM;
    wrow1 = W_att + (size_t)wr * DM;
  }

  // A staging: 256 chunks (64 rows x 4 kg), threads 0-255 only
  const int arow = tid >> 2;     // 0..63 (valid when tid<256)
  const int akg  = tid & 3;

  f32x4 pa0, pa1;
  auto load_A = [&](int k0) {
    if (tid < 256) {
      const float* p = &A[(size_t)(r0 + arow) * DM + k0 + akg * 8];
      pa0 = *reinterpret_cast<const f32x4*>(p);
      pa1 = *reinterpret_cast<const f32x4*>(p + 4);
    }
  };
  load_A(0);

  f32x4 acc[2][4] = {};

  for (int k = 0; k < 8; ++k) {
    const int k0 = k * BK;
    // ---- phase 1a: W JIT staging (L2 hits, 2 chunks/thread) ----
    {
      const float* p0 = wrow0 + k0 + wkg * 8;
      const f32x4 w00 = *reinterpret_cast<const f32x4*>(p0);
      const f32x4 w01 = *reinterpret_cast<const f32x4*>(p0 + 4);
      *reinterpret_cast<short8*>(Bs + wkg * 4096 + wr * 16) = cvt8(w00, w01);
      const float* p1 = wrow1 + k0 + wkg * 8;
      const f32x4 w10 = *reinterpret_cast<const f32x4*>(p1);
      const f32x4 w11 = *reinterpret_cast<const f32x4*>(p1 + 4);
      *reinterpret_cast<short8*>(Bs + wkg * 4096 + (wr + 128) * 16) =
          cvt8(w10, w11);
    }
    // ---- phase 1b: A convert + LDS write (threads 0-255) ----
    if (tid < 256) {
      *reinterpret_cast<short8*>(As + akg * 1024 + arow * 16) = cvt8(pa0, pa1);
    }
    // issue next A tile's HBM loads (ride across barrier + MFMA)
    if (k < 7) load_A(k0 + BK);

    asm volatile("s_waitcnt lgkmcnt(0)" ::: "memory");
    __builtin_amdgcn_sched_barrier(0);
    __builtin_amdgcn_s_barrier();
    __builtin_amdgcn_sched_barrier(0);

    // ---- phase 2: fragments + MFMA (k-major LDS, conflict-free) ----
    {
      const int kgl = lane >> 4;     // 0..3
      const int rl  = lane & 15;
      short8 af[2], bfr[4];
      #pragma unroll
      for (int mi = 0; mi < 2; ++mi)
        af[mi] = *reinterpret_cast<const short8*>(
            As + kgl * 1024 + (wm * 32 + mi * 16 + rl) * 16);
      #pragma unroll
      for (int ni = 0; ni < 4; ++ni)
        bfr[ni] = *reinterpret_cast<const short8*>(
            Bs + kgl * 4096 + (wn * 64 + ni * 16 + rl) * 16);
      #pragma unroll
      for (int mi = 0; mi < 2; ++mi)
        #pragma unroll
        for (int ni = 0; ni < 4; ++ni)
          acc[mi][ni] = __builtin_amdgcn_mfma_f32_16x16x32_bf16(
              af[mi], bfr[ni], acc[mi][ni], 0, 0, 0);
    }

    asm volatile("s_waitcnt lgkmcnt(0)" ::: "memory");
    __builtin_amdgcn_sched_barrier(0);
    __builtin_amdgcn_s_barrier();
    __builtin_amdgcn_sched_barrier(0);
  }

  // ---- epilogue: two 128-col halves through the 17.4 KB LDS tile ----
  #pragma unroll
  for (int hh = 0; hh < 2; ++hh) {
    if ((wn >> 1) == hh) {
      #pragma unroll
      for (int mi = 0; mi < 2; ++mi) {
        const int row = wm * 32 + mi * 16 + (lane >> 4) * 4;
        #pragma unroll
        for (int ni = 0; ni < 4; ++ni) {
          const int coll = (wn & 1) * 64 + ni * 16 + (lane & 15);
          #pragma unroll
          for (int j = 0; j < 4; ++j)
            sm.c[(row + j) * 136 + coll] = (_Float16)(acc[mi][ni][j] + bv[ni]);
        }
      }
    }
    __syncthreads();
    #pragma unroll
    for (int i = 0; i < 2; ++i) {
      const int ch  = tid + i * 512;   // 0..1023
      const int row = ch >> 4;         // 0..63
      const int cc  = ch & 15;         // 16B chunk within the 128-col half
      const half8 v = *reinterpret_cast<const half8*>(&sm.c[row * 136 + cc * 8]);
      if (isv) {
        const int h = hh * 4 + (cc >> 2);   // global head 0..7
        _Float16* dst = out_val +
            ((size_t)(vbatch * 8 + h) * S_TOT + vtrow0 + row) * 32 + (cc & 3) * 8;
        *reinterpret_cast<half8*>(dst) = v;
      } else {
        *reinterpret_cast<half8*>(
            &out_prj[(size_t)(r0 + row) * DM + hh * 128 + cc * 8]) = v;
      }
    }
    __syncthreads();
  }
}

// ---------------------------------------------------------------------------
// Sampler v7 (unchanged R14). Measured S ~= 23.7 us, invariant under MLP
// depth (R10), layout (R11), and segment-size (R14) restructures ->
// scattered-gather granule-rate floor; not touched.
// ---------------------------------------------------------------------------
__global__ __launch_bounds__(512) void sample_k(
    const _Float16* __restrict__ proj,    // (N*LQ, 256) f16
    const float* __restrict__ refp,       // (N, LQ, 4)
    const _Float16* __restrict__ value,   // (N, 8, 3840, 32) f16 head-major
    float* __restrict__ out)              // (N, LQ, 256)
{
  __shared__ uint2 tap_s[8][136];   // [q][m*17 + tap], 8.7 KB

  const int d     = blockIdx.x;
  const int n     = d & 7;
  const int chunk = d >> 3;
  const int row0q = n * LQn + chunk * 8;
  const int t     = threadIdx.x;

  const int lens[4]   = {2048, 1024, 512, 256};
  const int starts[4] = {0, 2048, 3072, 3584};

  if (t < 256) {
    const int q   = t >> 5;
    const int m   = (t >> 2) & 7;
    const int sub = t & 3;              // == level l
    const int j0  = m * 16 + sub * 4;
    const size_t prow = (size_t)(row0q + q) * DM;

    const half4 offv = *reinterpret_cast<const half4*>(&proj[prow + j0]);
    const half4 lgv  = *reinterpret_cast<const half4*>(&proj[prow + 128 + j0]);
    float lg[4], off[4];
    #pragma unroll
    for (int i = 0; i < 4; ++i) { lg[i] = (float)lgv[i]; off[i] = (float)offv[i]; }

    float mx = fmaxf(fmaxf(lg[0], lg[1]), fmaxf(lg[2], lg[3]));
    mx = fmaxf(mx, __shfl_xor(mx, 1));
    mx = fmaxf(mx, __shfl_xor(mx, 2));
    float e[4], s = 0.f;
    #pragma unroll
    for (int i = 0; i < 4; ++i) { e[i] = __expf(lg[i] - mx); s += e[i]; }
    s += __shfl_xor(s, 1);
    s += __shfl_xor(s, 2);
    const float inv = 1.f / s;

    const int   T  = lens[sub];
    const int   st = starts[sub];
    const float fT = (float)T;
    const float rf = refp[(size_t)(row0q + q) * 4 + sub];
    #pragma unroll
    for (int i = 0; i < 4; ++i) {
      const float a  = e[i] * inv;
      const float ix = fmaf(rf, fT, off[i] - 0.5f);
      const float fl = floorf(ix);
      const float w1 = ix - fl;
      const int   i0 = (int)fl;
      const int   i1 = i0 + 1;
      const float wa = (i0 >= 0 && i0 < T) ? a * (1.f - w1) : 0.f;
      const float wb = (i1 >= 0 && i1 < T) ? a * w1 : 0.f;
      const int   base = min(max(i0, 0), T - 2);
      const float w_lo = (i0 == base) ? wa : ((i1 == base) ? wb : 0.f);
      const float w_hi = (i1 == base + 1) ? wb : ((i0 == base + 1) ? wa : 0.f);
      union { half2v h; unsigned u; } pw;
      pw.h.x = (_Float16)w_lo; pw.h.y = (_Float16)w_hi;
      uint2 ent; ent.x = pw.u; ent.y = (unsigned)((st + base) * 64);
      tap_s[q][m * 17 + sub * 4 + i] = ent;
    }
  }
  __syncthreads();

  const int q = t >> 6;           // wave id = query
  const int l = t & 63;
  const int m = l >> 3;           // head
  const int j = l & 7;            // 0..3 row base chunks, 4..7 row base+1
  const char* vb = reinterpret_cast<const char*>(value) +
                   (size_t)(n * 8 + m) * S_TOT * 64 + j * 16;

  uint2 e[16];
  #pragma unroll
  for (int i = 0; i < 16; ++i) e[i] = tap_s[q][m * 17 + i];

  float acc[8] = {};
  half8 v[8];
  #pragma unroll
  for (int i = 0; i < 8; ++i)
    v[i] = *reinterpret_cast<const half8*>(vb + e[i].y);

  #pragma unroll
  for (int i = 0; i < 16; ++i) {
    union { unsigned u; half2v h; } pw; pw.u = e[i].x;
    const float w = (float)((l & 4) ? pw.h.y : pw.h.x);
    const half8 a0 = v[i & 7];
    if (i < 8)
      v[i & 7] = *reinterpret_cast<const half8*>(vb + e[i + 8].y);
    #pragma unroll
    for (int jj = 0; jj < 8; ++jj)
      acc[jj] = fmaf(w, (float)a0[jj], acc[jj]);
  }

  #pragma unroll
  for (int jj = 0; jj < 8; ++jj) acc[jj] += __shfl_xor(acc[jj], 4);

  if ((l & 4) == 0) {
    float* op = &out[(size_t)(row0q + q) * DM + m * 32 + j * 8];
    f32x4 o0 = {acc[0], acc[1], acc[2], acc[3]};
    f32x4 o1 = {acc[4], acc[5], acc[6], acc[7]};
    *reinterpret_cast<f32x4*>(op)     = o0;
    *reinterpret_cast<f32x4*>(op + 4) = o1;
  }
}

}  // namespace

extern "C" void kernel_launch(void* const* d_in, const int* in_sizes, int n_in,
                              void* d_out, int out_size, void* d_ws, size_t ws_size,
                              hipStream_t stream) {
  const float* query  = (const float*)d_in[0];   // (8,2048,256)
  const float* refp   = (const float*)d_in[1];   // (8,2048,4,1)
  const float* inflat = (const float*)d_in[2];   // (8,3840,256)
  const float* W_val  = (const float*)d_in[5];   // (256,256)
  const float* b_val  = (const float*)d_in[6];   // (256,)
  const float* W_off  = (const float*)d_in[7];   // (128,256)
  const float* b_off  = (const float*)d_in[8];   // (128,)
  const float* W_attn = (const float*)d_in[9];   // (128,256)
  const float* b_attn = (const float*)d_in[10];  // (128,)
  float* out = (float*)d_out;

  _Float16* value_h = (_Float16*)d_ws;
  _Float16* proj_h  = (_Float16*)((char*)d_ws +
                      (size_t)NB * S_TOT * DM * sizeof(_Float16));

  // merged GEMM: 480 value + 256 proj blocks of 64x256 (A read once,
  // 92 blocks/XCD -> ~96% CU utilization), XCD-aligned
  gemm_bf16_k<<<dim3(736), dim3(512), 0, stream>>>(
      inflat, query, W_val, b_val, W_off, b_off, W_attn, b_attn,
      value_h, proj_h);

  // sampler v7: 128 B-contiguous tap loads
  sample_k<<<dim3(NB * LQn / 8), dim3(512), 0, stream>>>(
      proj_h, refp, value_h, out);
}

// Round 17
// 41.833 us; speedup vs baseline: 1.1016x; 1.0321x over previous
//
#include <hip/hip_runtime.h>
#include <hip/hip_bf16.h>
#include <cstddef>

namespace {

constexpr int NB    = 8;
constexpr int LQn   = 2048;
constexpr int DM    = 256;
constexpr int S_TOT = 3840;   // 2048+1024+512+256

typedef __attribute__((ext_vector_type(8))) short  short8;
typedef __attribute__((ext_vector_type(4))) float  f32x4;
typedef __attribute__((ext_vector_type(8))) _Float16 half8;
typedef __attribute__((ext_vector_type(4))) _Float16 half4;
typedef __attribute__((ext_vector_type(2))) _Float16 half2v;

// pack 4+4 f32 -> 8 bf16 via native v_cvt_pk_bf16_f32
union BF8 { __hip_bfloat162 h2[4]; short8 s8; };
__device__ inline short8 cvt8(const f32x4 a, const f32x4 b) {
  BF8 r;
  r.h2[0] = __float22bfloat162_rn(make_float2(a[0], a[1]));
  r.h2[1] = __float22bfloat162_rn(make_float2(a[2], a[3]));
  r.h2[2] = __float22bfloat162_rn(make_float2(b[0], b[1]));
  r.h2[3] = __float22bfloat162_rn(make_float2(b[2], b[3]));
  return r.s8;
}

// ---------------------------------------------------------------------------
// FINAL (revert to R10, the empirical best at 41.75 us across R10-R16's
// 41.75-43.2 plateau). Merged bf16-MFMA GEMM (value + proj), f16 output.
// 1D grid of 736 blocks, XCD-aligned mapping (id%8 == batch == XCD; col
// partners 8 apart -> same XCD). Tile 128x128, BK=64, 4 waves (2x2), 4x4
// frags of mfma_f32_16x16x32_bf16. LDS [128][64] bf16, T2 XOR swizzle.
// W JIT-staged (L2-resident); A 1-k-step-ahead reg prefetch; raw s_barrier
// + lgkmcnt(0) only (A's vmcnt outstanding across the MFMA phase).
// Plateau evidence: R12 (A-read-once), R15 (dbuf), R16 (64-row balance)
// all landed 42.1-46.1 -> G ~= 18.4 us is structural (HBM floor ~12-13 +
// launch/tail); S = 23.7 us invariant under R10/R11/R14 restructures.
// ---------------------------------------------------------------------------
union SMem {
  struct { short A[128 * 64]; short B[128 * 64]; } ab;   // 32 KB k-loop
  _Float16 c[128 * 136];                                  // 34 KB epilogue
};

__global__ __launch_bounds__(256, 3) void gemm_bf16_k(
    const float* __restrict__ A_val, const float* __restrict__ A_prj,
    const float* __restrict__ W_val, const float* __restrict__ b_val,
    const float* __restrict__ W_off, const float* __restrict__ b_off,
    const float* __restrict__ W_att, const float* __restrict__ b_att,
    _Float16* __restrict__ out_val, _Float16* __restrict__ out_prj)
{
  __shared__ SMem sm;
  short* As = sm.ab.A;
  short* Bs = sm.ab.B;

  const int tid  = threadIdx.x;
  const int lane = tid & 63;
  const int wid  = tid >> 6;
  const int wm   = wid >> 1;
  const int wn   = wid & 1;

  const int id = blockIdx.x;
  const float *A, *W, *bias;
  _Float16* out;
  int r0, c0;
  if (id < 480) {
    const int x = id & 7;            // XCD == batch
    const int s = id >> 3;           // 0..59
    const int rb = x * 30 + (s >> 1);
    const int c  = s & 1;
    A = A_val; out = out_val; r0 = rb * 128; c0 = c * 128;
    W = W_val + (size_t)c0 * DM; bias = b_val + c0;
  } else {
    const int j = id - 480;
    const int x = j & 7;             // XCD == batch
    const int s = j >> 3;            // 0..31
    const int rb = x * 16 + (s >> 1);
    const int c  = s & 1;
    A = A_prj; out = out_prj; r0 = rb * 128; c0 = c * 128;
    W = c ? W_att : W_off; bias = c ? b_att : b_off;
  }

  f32x4 acc[4][4] = {};

  float bv[4];
  #pragma unroll
  for (int ni = 0; ni < 4; ++ni)
    bv[ni] = bias[wn * 64 + ni * 16 + (lane & 15)];

  f32x4 pa0[4], pa1[4];    // A prefetch only (W is JIT-staged)

  auto load_A = [&](int k0) {
    #pragma unroll
    for (int i = 0; i < 4; ++i) {
      const int ch  = tid + i * 256;   // 0..1023
      const int row = ch >> 3;         // 0..127
      const int kg  = ch & 7;          // 0..7
      const size_t goff = (size_t)(r0 + row) * DM + k0 + kg * 8;
      pa0[i] = *reinterpret_cast<const f32x4*>(&A[goff]);
      pa1[i] = *reinterpret_cast<const f32x4*>(&A[goff + 4]);
    }
  };

  load_A(0);

  for (int k = 0; k < 4; ++k) {
    const int k0 = k * 64;
    // phase 1a: W JIT staging (L2-hit loads, low register footprint)
    #pragma unroll 2
    for (int i = 0; i < 4; ++i) {
      const int ch  = tid + i * 256;
      const int row = ch >> 3;
      const int kg  = ch & 7;
      const size_t woff = (size_t)row * DM + k0 + kg * 8;
      const f32x4 w0 = *reinterpret_cast<const f32x4*>(&W[woff]);
      const f32x4 w1 = *reinterpret_cast<const f32x4*>(&W[woff + 4]);
      const short8 sw = cvt8(w0, w1);
      const int byte = row * 128 + ((kg * 16) ^ ((row & 7) << 4));
      *reinterpret_cast<short8*>(reinterpret_cast<char*>(Bs) + byte) = sw;
    }
    // phase 1b: A convert + LDS write (data-dep wait on pa_k)
    #pragma unroll
    for (int i = 0; i < 4; ++i) {
      const int ch  = tid + i * 256;
      const int row = ch >> 3;
      const int kg  = ch & 7;
      const short8 sa = cvt8(pa0[i], pa1[i]);
      const int byte = row * 128 + ((kg * 16) ^ ((row & 7) << 4));
      *reinterpret_cast<short8*>(reinterpret_cast<char*>(As) + byte) = sa;
    }
    // issue next A tile's HBM loads; stay in flight across barrier + MFMA
    if (k < 3) load_A(k0 + 64);

    asm volatile("s_waitcnt lgkmcnt(0)" ::: "memory");
    __builtin_amdgcn_sched_barrier(0);
    __builtin_amdgcn_s_barrier();
    __builtin_amdgcn_sched_barrier(0);

    // phase 2: fragments + MFMA
    #pragma unroll
    for (int ks = 0; ks < 2; ++ks) {
      const int kb = (ks * 32 + (lane >> 4) * 8) * 2;
      short8 af[4], bf[4];
      #pragma unroll
      for (int mi = 0; mi < 4; ++mi) {
        const int row = wm * 64 + mi * 16 + (lane & 15);
        const int byte = row * 128 + (kb ^ ((row & 7) << 4));
        af[mi] = *reinterpret_cast<const short8*>(
            reinterpret_cast<const char*>(As) + byte);
      }
      #pragma unroll
      for (int ni = 0; ni < 4; ++ni) {
        const int col = wn * 64 + ni * 16 + (lane & 15);
        const int byte = col * 128 + (kb ^ ((col & 7) << 4));
        bf[ni] = *reinterpret_cast<const short8*>(
            reinterpret_cast<const char*>(Bs) + byte);
      }
      #pragma unroll
      for (int mi = 0; mi < 4; ++mi)
        #pragma unroll
        for (int ni = 0; ni < 4; ++ni)
          acc[mi][ni] = __builtin_amdgcn_mfma_f32_16x16x32_bf16(
              af[mi], bf[ni], acc[mi][ni], 0, 0, 0);
    }

    asm volatile("s_waitcnt lgkmcnt(0)" ::: "memory");
    __builtin_amdgcn_sched_barrier(0);
    __builtin_amdgcn_s_barrier();
    __builtin_amdgcn_sched_barrier(0);
  }

  // epilogue: acc -> f16 LDS tile [128][136] -> coalesced 16B stores
  #pragma unroll
  for (int mi = 0; mi < 4; ++mi) {
    const int row = wm * 64 + mi * 16 + (lane >> 4) * 4;
    #pragma unroll
    for (int ni = 0; ni < 4; ++ni) {
      const int col = wn * 64 + ni * 16 + (lane & 15);
      #pragma unroll
      for (int j = 0; j < 4; ++j)
        sm.c[(row + j) * 136 + col] = (_Float16)(acc[mi][ni][j] + bv[ni]);
    }
  }
  __syncthreads();
  #pragma unroll
  for (int i = 0; i < 8; ++i) {
    const int ch  = tid + i * 256;   // 0..2047
    const int row = ch >> 4;         // 0..127
    const int cc  = ch & 15;         // 16B col-chunk
    const half8 v = *reinterpret_cast<const half8*>(&sm.c[row * 136 + cc * 8]);
    *reinterpret_cast<half8*>(&out[(size_t)(r0 + row) * DM + c0 + cc * 8]) = v;
  }
}

// ---------------------------------------------------------------------------
// Sampler v5 (R10, empirical best). Block = 512 threads = 8 queries,
// XCD-swizzled grid (n = blockIdx&7 == XCD, matching the GEMM's mapping).
// Prep (t<256): (q,m,sub-level) -> 4-lane shfl softmax -> tap table in LDS.
// Gather: thread (q=wave, m, dg, th) does 8 taps, batch-issued depth-2
// pipeline (8 VMEM in flight); shfl_xor(4) partner merge.
// S = 23.7 us, invariant under MLP-depth/layout/segment restructures ->
// scattered-gather rate floor at f16 (fp8 would breach the error budget).
// ---------------------------------------------------------------------------
__global__ __launch_bounds__(512) void sample_k(
    const _Float16* __restrict__ proj,    // (N*LQ, 256) f16
    const float* __restrict__ refp,       // (N, LQ, 4)
    const _Float16* __restrict__ value,   // (N, 3840, 256) f16, c = m*32+d
    float* __restrict__ out)              // (N, LQ, 256)
{
  __shared__ uint4 tap_s[8][136];   // [q][m*17 + tap], 17.4 KB

  const int d     = blockIdx.x;
  const int n     = d & 7;
  const int chunk = d >> 3;
  const int row0q = n * LQn + chunk * 8;
  const int t     = threadIdx.x;

  const int lens[4]   = {2048, 1024, 512, 256};
  const int starts[4] = {0, 2048, 3072, 3584};

  // ---- prep: softmax + tap table ----
  if (t < 256) {
    const int q   = t >> 5;
    const int m   = (t >> 2) & 7;
    const int sub = t & 3;              // == level l
    const int j0  = m * 16 + sub * 4;
    const size_t prow = (size_t)(row0q + q) * DM;

    const half4 offv = *reinterpret_cast<const half4*>(&proj[prow + j0]);
    const half4 lgv  = *reinterpret_cast<const half4*>(&proj[prow + 128 + j0]);
    float lg[4], off[4];
    #pragma unroll
    for (int i = 0; i < 4; ++i) { lg[i] = (float)lgv[i]; off[i] = (float)offv[i]; }

    float mx = fmaxf(fmaxf(lg[0], lg[1]), fmaxf(lg[2], lg[3]));
    mx = fmaxf(mx, __shfl_xor(mx, 1));
    mx = fmaxf(mx, __shfl_xor(mx, 2));
    float e[4], s = 0.f;
    #pragma unroll
    for (int i = 0; i < 4; ++i) { e[i] = __expf(lg[i] - mx); s += e[i]; }
    s += __shfl_xor(s, 1);
    s += __shfl_xor(s, 2);
    const float inv = 1.f / s;

    const int   T  = lens[sub];
    const int   st = starts[sub];
    const float fT = (float)T;
    const float rf = refp[(size_t)(row0q + q) * 4 + sub];
    #pragma unroll
    for (int i = 0; i < 4; ++i) {
      const float a  = e[i] * inv;
      const float ix = fmaf(rf, fT, off[i] - 0.5f);
      const float fl = floorf(ix);
      const float w1 = ix - fl;
      const int   i0 = (int)fl;
      const int   i1 = i0 + 1;
      const float wa = (i0 >= 0 && i0 < T) ? a * (1.f - w1) : 0.f;
      const float wb = (i1 >= 0 && i1 < T) ? a * w1 : 0.f;
      const int   r0b = (st + min(max(i0, 0), T - 1)) * 512;
      const int   r1b = (st + min(max(i1, 0), T - 1)) * 512;
      union { half2v h; unsigned u; } pw;
      pw.h.x = (_Float16)wa; pw.h.y = (_Float16)wb;
      uint4 ent; ent.x = pw.u; ent.y = (unsigned)r0b; ent.z = (unsigned)r1b; ent.w = 0u;
      tap_s[q][m * 17 + sub * 4 + i] = ent;
    }
  }
  __syncthreads();

  // ---- gather (batch-issued, depth-2 pipelined) ----
  const int q  = t >> 6;          // wave id = query
  const int l  = t & 63;
  const int m  = l >> 3;
  const int dg = l & 3;
  const int th = (l >> 2) & 1;    // tap-half
  const char* vb = reinterpret_cast<const char*>(value) +
                   (size_t)n * S_TOT * 512 + m * 64 + dg * 16;

  uint4 e[8];
  #pragma unroll
  for (int i = 0; i < 8; ++i) e[i] = tap_s[q][m * 17 + th * 8 + i];

  float acc[8] = {};
  half8 v0[4], v1[4];
  #pragma unroll
  for (int i = 0; i < 4; ++i) {
    v0[i] = *reinterpret_cast<const half8*>(vb + e[i].y);
    v1[i] = *reinterpret_cast<const half8*>(vb + e[i].z);
  }
  #pragma unroll
  for (int i = 0; i < 8; ++i) {
    const int s = i & 3;
    union { unsigned u; half2v h; } pw; pw.u = e[i].x;
    const float wa = (float)pw.h.x;
    const float wb = (float)pw.h.y;
    const half8 a0 = v0[s];
    const half8 a1 = v1[s];
    if (i < 4) {   // prefetch second half while consuming first
      v0[s] = *reinterpret_cast<const half8*>(vb + e[i + 4].y);
      v1[s] = *reinterpret_cast<const half8*>(vb + e[i + 4].z);
    }
    #pragma unroll
    for (int j = 0; j < 8; ++j)
      acc[j] = fmaf(wa, (float)a0[j], fmaf(wb, (float)a1[j], acc[j]));
  }

  #pragma unroll
  for (int j = 0; j < 8; ++j) acc[j] += __shfl_xor(acc[j], 4);

  if (th == 0) {
    float* op = &out[(size_t)(row0q + q) * DM + m * 32 + dg * 8];
    f32x4 o0 = {acc[0], acc[1], acc[2], acc[3]};
    f32x4 o1 = {acc[4], acc[5], acc[6], acc[7]};
    *reinterpret_cast<f32x4*>(op)     = o0;
    *reinterpret_cast<f32x4*>(op + 4) = o1;
  }
}

}  // namespace

extern "C" void kernel_launch(void* const* d_in, const int* in_sizes, int n_in,
                              void* d_out, int out_size, void* d_ws, size_t ws_size,
                              hipStream_t stream) {
  const float* query  = (const float*)d_in[0];   // (8,2048,256)
  const float* refp   = (const float*)d_in[1];   // (8,2048,4,1)
  const float* inflat = (const float*)d_in[2];   // (8,3840,256)
  const float* W_val  = (const float*)d_in[5];   // (256,256)
  const float* b_val  = (const float*)d_in[6];   // (256,)
  const float* W_off  = (const float*)d_in[7];   // (128,256)
  const float* b_off  = (const float*)d_in[8];   // (128,)
  const float* W_attn = (const float*)d_in[9];   // (128,256)
  const float* b_attn = (const float*)d_in[10];  // (128,)
  float* out = (float*)d_out;

  // workspace: value f16 (30720*256 = 15.73 MB) | proj f16 (8.4 MB)
  _Float16* value_h = (_Float16*)d_ws;
  _Float16* proj_h  = (_Float16*)((char*)d_ws +
                      (size_t)NB * S_TOT * DM * sizeof(_Float16));

  // merged GEMM: 480 value blocks + 256 proj blocks (XCD-aligned mapping)
  gemm_bf16_k<<<dim3(736), dim3(256), 0, stream>>>(
      inflat, query, W_val, b_val, W_off, b_off, W_attn, b_attn,
      value_h, proj_h);

  // softmax + bilinear sampling + head-mix (XCD-aligned to the GEMM's L2)
  sample_k<<<dim3(NB * LQn / 8), dim3(512), 0, stream>>>(
      proj_h, refp, value_h, out);
}